// Round 5
// baseline (214.575 us; speedup 1.0000x reference)
//
#include <hip/hip_runtime.h>
#include <hip/hip_bf16.h>

// N,C,K,P,Q,PS = 32,128,128,64,64,3
#define NN 32
#define CCH 128
#define KK 128
#define PP 64
#define QQ 64

typedef __bf16 bf16x8 __attribute__((ext_vector_type(8)));
typedef float f32x16 __attribute__((ext_vector_type(16)));
typedef float f32x4 __attribute__((ext_vector_type(4)));

// Workspace:
//   xT: [N][8 cc][P][Q][16 c] bf16 = 33,554,432 B   (c-chunk-major!)
//   Wf: [8 cc][9 t][4 kb][64 lane][8 bf16] = 294,912 B
#define XT_ELEMS (32ull * 64 * 64 * 128)

// ---------- prep 1: x (NCHW f32) -> xT ([n][cc][p][q][16c] bf16) ----------
// (unchanged — verified)
__global__ __launch_bounds__(256) void prep_x(const float* __restrict__ x,
                                              __bf16* __restrict__ xT) {
    __shared__ float tile[128 * 64];
    const int t = threadIdx.x;
    const int p = blockIdx.x;
    const int n = blockIdx.y;

#pragma unroll
    for (int pass = 0; pass < 8; ++pass) {
        int idx = pass * 256 + t;
        int qf = idx & 15;
        int c  = idx >> 4;
        f32x4 v = *(const f32x4*)(x + (((size_t)n * CCH + c) * PP + p) * QQ + qf * 4);
        int key = ((c >> 3) & 15) * 4;
        *(f32x4*)(tile + c * 64 + ((qf * 4) ^ key)) = v;
    }
    __syncthreads();

#pragma unroll
    for (int pass = 0; pass < 4; ++pass) {
        int cc   = pass * 2 + (t >> 7);
        int rem  = t & 127;
        int q    = rem >> 1;
        int half = rem & 1;
        int c0   = cc * 16 + half * 8;
        int key  = ((c0 >> 3) & 15) * 4;
        bf16x8 o;
#pragma unroll
        for (int j = 0; j < 8; ++j) o[j] = (__bf16)tile[(c0 + j) * 64 + (q ^ key)];
        *(bf16x8*)(xT + ((((size_t)n * 8 + cc) * PP + p) * QQ + q) * 16 + half * 8) = o;
    }
}

// ---------- prep 2: W -> Wf fragment order (unchanged — verified) ----------
__global__ __launch_bounds__(256) void prep_w(const float* __restrict__ W,
                                              __bf16* __restrict__ Wf) {
    const int id = blockIdx.x * 256 + threadIdx.x;  // 18432
    const int lane = id & 63;
    const int r1   = id >> 6;
    const int kb   = r1 & 3;
    const int r2   = r1 >> 2;
    const int t    = r2 % 9;
    const int cc   = r2 / 9;

    const int k  = kb * 32 + (lane & 31);
    const int c0 = cc * 16 + (lane >> 5) * 8;

    bf16x8 o;
#pragma unroll
    for (int j = 0; j < 8; ++j)
        o[j] = (__bf16)W[(size_t)k * (CCH * 9) + (size_t)(c0 + j) * 9 + t];
    ((bf16x8*)Wf)[id] = o;
}

// ---------- main: implicit GEMM conv, NO LDS / NO BARRIERS in main loop ----------
// Evidence R0-R4: 69-72 us invariant under sync/epilogue/W-path changes;
// MfmaUtil 21% = 15.4 us of matrix work (32 cyc/MFMA/SIMD) + 4.5x stall.
// Diagnosis: per-cc barrier phase-locks all waves -> synchronized LDS-port
// bursts (B ds_reads were 4-8-way bank conflicted: banks (8m)&31 in {0,8,16,24})
// with the matrix pipe idle in between; barrier re-locks phases every cc.
// Fix: B fragments load STRAIGHT from global xT (contiguous 1 KB/wave-request,
// L3-resident), like A from Wf (proven free in R4). Main loop = loads + MFMA,
// zero __syncthreads, zero ds_read -> waves free-run, compiler hoists loads
// across ri/cc with no LDS hazards. q-edge (q_in=-1|64) = cndmask zero on the
// 2 affected fragments. LDS: only 16 KB per-wave epilogue scratch.
__global__ __launch_bounds__(256, 2) void conv_main(const __bf16* __restrict__ xT,
                                                    const __bf16* __restrict__ Wf,
                                                    const float* __restrict__ per,
                                                    float* __restrict__ out) {
    __shared__ __align__(16) char scr_lds[4][4096];  // per-wave epilogue scratch

    const int tid  = threadIdx.x;
    const int lane = tid & 63;
    const int w    = tid >> 6;   // 0..3
    const int kbs  = w & 1;
    const int pb   = w >> 1;     // 0..1
    const int n    = blockIdx.y;
    const int p0   = blockIdx.x * 4;
    const int m    = lane & 31;
    const int half = lane >> 5;

    bf16x8 bz;
#pragma unroll
    for (int j = 0; j < 8; ++j) bz[j] = (__bf16)0.f;

    f32x16 acc[2][2][2];  // [oi][kb][qb]
#pragma unroll
    for (int a = 0; a < 2; ++a)
#pragma unroll
        for (int b = 0; b < 2; ++b)
#pragma unroll
            for (int c = 0; c < 2; ++c)
#pragma unroll
                for (int e = 0; e < 16; ++e) acc[a][b][c][e] = 0.f;

    const char* xb = (const char*)xT + ((size_t)n * 8) * PP * QQ * 32;  // + cc*131072

    // W fragment base for this wave: frag id = cc*2304 + (t*4 + kbs*2 + kb)*64 + lane
    const bf16x8* wg = (const bf16x8*)Wf + kbs * 128 + lane;

    // one cc-step; A from Wf (L2-hot), B from xT (L3-hot), all into registers
    auto compute = [&](int cc) {
        const char* xcc = xb + (size_t)cc * (PP * QQ * 32);
        const bf16x8* wc = wg + (size_t)cc * 2304;

        bf16x8 a_cur[3][2], a_prev[3][2];
#pragma unroll
        for (int ri = 0; ri < 4; ++ri) {
            const int r  = p0 + pb * 2 + ri - 1;   // global input row
            const bool rok = ((unsigned)r < (unsigned)PP);  // wave-uniform

            // B frags direct from global: row r, q_in = qb*32 + m + dq - 1
            bf16x8 b[3][2];
            if (rok) {
                const char* xrow = xcc + (size_t)r * 2048 + half * 16;
#pragma unroll
                for (int dq = 0; dq < 3; ++dq)
#pragma unroll
                    for (int qb = 0; qb < 2; ++qb) {
                        int q_in = qb * 32 + m + dq - 1;
                        bool ok  = ((unsigned)q_in < (unsigned)QQ);  // per-lane
                        int qc   = ok ? q_in : 0;
                        bf16x8 v = *(const bf16x8*)(xrow + qc * 32);
                        b[dq][qb] = ok ? v : bz;
                    }
            }

            // A frags for tap row ri (consumed by oi=0 now, oi=1 at ri+1)
            if (ri < 3) {
#pragma unroll
                for (int dq = 0; dq < 3; ++dq)
#pragma unroll
                    for (int kb = 0; kb < 2; ++kb)
                        a_cur[dq][kb] = wc[((ri * 3 + dq) * 4 + kb) * 64];  // L2 hit
            }

            if (rok) {
                if (ri >= 1) {
#pragma unroll
                    for (int dq = 0; dq < 3; ++dq)
#pragma unroll
                        for (int kb = 0; kb < 2; ++kb)
#pragma unroll
                            for (int qb = 0; qb < 2; ++qb)
                                acc[1][kb][qb] = __builtin_amdgcn_mfma_f32_32x32x16_bf16(
                                    a_prev[dq][kb], b[dq][qb], acc[1][kb][qb], 0, 0, 0);
                }
                if (ri < 3) {
#pragma unroll
                    for (int dq = 0; dq < 3; ++dq)
#pragma unroll
                        for (int kb = 0; kb < 2; ++kb)
#pragma unroll
                            for (int qb = 0; qb < 2; ++qb)
                                acc[0][kb][qb] = __builtin_amdgcn_mfma_f32_32x32x16_bf16(
                                    a_cur[dq][kb], b[dq][qb], acc[0][kb][qb], 0, 0, 0);
                }
            }

            if (ri < 3) {
#pragma unroll
                for (int dq = 0; dq < 3; ++dq)
#pragma unroll
                    for (int kb = 0; kb < 2; ++kb) a_prev[dq][kb] = a_cur[dq][kb];
            }
        }
    };

    for (int cc = 0; cc < 7; ++cc) compute(cc);

    // ---- epilogue helpers (verified mapping, unchanged) ----
    auto tile_addr = [&](int it, int j) -> size_t {
        int oi = it >> 2, kbi = (it >> 1) & 1, qb = it & 1;
        int prow = p0 + pb * 2 + oi;
        int k = (kbs * 2 + kbi) * 32 + (lane >> 3) + j * 8;
        int q = qb * 32 + (lane & 7) * 4;
        return (((size_t)n * KK + k) * PP + prow) * QQ + q;
    };

    float* scr = (float*)scr_lds[w];  // private per wave, no cross-wave hazard

    auto process = [&](int it, f32x4 (&pv)[4]) {
        int oi = it >> 2, kbi = (it >> 1) & 1, qb = it & 1;
        f32x16 v = acc[oi][kbi][qb];
#pragma unroll
        for (int r = 0; r < 16; ++r) {
            int kl = (r & 3) + 8 * (r >> 2) + 4 * half;
            scr[kl * 32 + ((((m >> 2) ^ (kl & 7)) << 2) | (m & 3))] = v[r];
        }
        // same-wave LDS RAW: compiler inserts lgkmcnt wait
#pragma unroll
        for (int j = 0; j < 4; ++j) {
            int kl = (lane >> 3) + j * 8;
            f32x4 d = *(const f32x4*)(scr + kl * 32 + (((lane & 7) ^ (kl & 7)) << 2));
            f32x4 s = d + pv[j];
            __builtin_nontemporal_store(s, (f32x4*)(out + tile_addr(it, j)));
        }
    };

    // ---- peeled cc=7 with depth-1 per prefetch (32 VGPR, no spill) ----
    f32x4 pv0[4], pv1[4];
#pragma unroll
    for (int j = 0; j < 4; ++j) pv0[j] = *(const f32x4*)(per + tile_addr(0, j));

    compute(7);

#pragma unroll
    for (int itp = 0; itp < 4; ++itp) {
        const int itA = itp * 2, itB = itp * 2 + 1;
#pragma unroll
        for (int j = 0; j < 4; ++j) pv1[j] = *(const f32x4*)(per + tile_addr(itB, j));
        process(itA, pv0);
        if (itp < 3) {
#pragma unroll
            for (int j = 0; j < 4; ++j)
                pv0[j] = *(const f32x4*)(per + tile_addr(itA + 2, j));
        }
        process(itB, pv1);
    }
}

extern "C" void kernel_launch(void* const* d_in, const int* in_sizes, int n_in,
                              void* d_out, int out_size, void* d_ws, size_t ws_size,
                              hipStream_t stream) {
    const float* x   = (const float*)d_in[0];  // [32][128][64][64]
    const float* W   = (const float*)d_in[1];  // [128][1152]
    const float* per = (const float*)d_in[2];  // [32][128][64][64]
    float* out = (float*)d_out;

    __bf16* xT = (__bf16*)d_ws;
    __bf16* Wf = (__bf16*)((char*)d_ws + XT_ELEMS * 2);

    prep_x<<<dim3(PP, NN), 256, 0, stream>>>(x, xT);
    prep_w<<<dim3(72), 256, 0, stream>>>(W, Wf);
    conv_main<<<dim3(PP / 4, NN), 256, 0, stream>>>(xT, Wf, per, out);
}

// Round 6
// 214.356 us; speedup vs baseline: 1.0010x; 1.0010x over previous
//
#include <hip/hip_runtime.h>
#include <hip/hip_bf16.h>

// N,C,K,P,Q,PS = 32,128,128,64,64,3
#define NN 32
#define CCH 128
#define KK 128
#define PP 64
#define QQ 64

typedef __bf16 bf16x8 __attribute__((ext_vector_type(8)));
typedef float f32x16 __attribute__((ext_vector_type(16)));
typedef float f32x4 __attribute__((ext_vector_type(4)));

// Workspace:
//   xT: [N][8 cc][P][Q][16 c] bf16 = 33,554,432 B   (c-chunk-major!)
//   Wf: [8 cc][9 t][4 kb][64 lane][8 bf16] = 294,912 B
#define XT_ELEMS (32ull * 64 * 64 * 128)

// ---------- prep 1: x (NCHW f32) -> xT ([n][cc][p][q][16c] bf16) ----------
// (unchanged — verified)
__global__ __launch_bounds__(256) void prep_x(const float* __restrict__ x,
                                              __bf16* __restrict__ xT) {
    __shared__ float tile[128 * 64];
    const int t = threadIdx.x;
    const int p = blockIdx.x;
    const int n = blockIdx.y;

#pragma unroll
    for (int pass = 0; pass < 8; ++pass) {
        int idx = pass * 256 + t;
        int qf = idx & 15;
        int c  = idx >> 4;
        f32x4 v = *(const f32x4*)(x + (((size_t)n * CCH + c) * PP + p) * QQ + qf * 4);
        int key = ((c >> 3) & 15) * 4;
        *(f32x4*)(tile + c * 64 + ((qf * 4) ^ key)) = v;
    }
    __syncthreads();

#pragma unroll
    for (int pass = 0; pass < 4; ++pass) {
        int cc   = pass * 2 + (t >> 7);
        int rem  = t & 127;
        int q    = rem >> 1;
        int half = rem & 1;
        int c0   = cc * 16 + half * 8;
        int key  = ((c0 >> 3) & 15) * 4;
        bf16x8 o;
#pragma unroll
        for (int j = 0; j < 8; ++j) o[j] = (__bf16)tile[(c0 + j) * 64 + (q ^ key)];
        *(bf16x8*)(xT + ((((size_t)n * 8 + cc) * PP + p) * QQ + q) * 16 + half * 8) = o;
    }
}

// ---------- prep 2: W -> Wf fragment order (unchanged — verified) ----------
__global__ __launch_bounds__(256) void prep_w(const float* __restrict__ W,
                                              __bf16* __restrict__ Wf) {
    const int id = blockIdx.x * 256 + threadIdx.x;  // 18432
    const int lane = id & 63;
    const int r1   = id >> 6;
    const int kb   = r1 & 3;
    const int r2   = r1 >> 2;
    const int t    = r2 % 9;
    const int cc   = r2 / 9;

    const int k  = kb * 32 + (lane & 31);
    const int c0 = cc * 16 + (lane >> 5) * 8;

    bf16x8 o;
#pragma unroll
    for (int j = 0; j < 8; ++j)
        o[j] = (__bf16)W[(size_t)k * (CCH * 9) + (size_t)(c0 + j) * 9 + t];
    ((bf16x8*)Wf)[id] = o;
}

// ---------- main: implicit GEMM conv, OCCUPANCY round ----------
// R0-R5 evidence: 69-75 us invariant under sync/W-path/B-path/epilogue/VMEM-
// volume changes; always 2 waves/SIMD (acc 128 AGPR + ~120 VGPR = 248 regs,
// 512-slot SIMD RF). MFMA blocks its wave; each wave waits ~85% of its
// timeline; ONE partner wave (also waiting 85%) can't fill the pipe -> ~20%
// MfmaUtil forever. Fix = occupancy: halve per-wave state.
//   wave = 1 p-row x 64 k x 64 q -> acc[2][2] = 64 AGPR
//   block = 4 waves (256 thr) = 2 p-rows x 128 k; grid (32,32) = 1024 blocks
//   tap-granular load-use loop (no rotation arrays) -> ~48 array VGPR live
//   target total <=170 regs -> 3 blocks/CU (12 waves/CU); <=128 -> 4.
// B from LDS (block-shared, 4-cc halves of 33.8 KB, 4 barriers total);
// A from global Wf (L2-resident, proven free in R4/R5).
#define XPITCH 2112  // bytes per padded x row in LDS (66 * 32)
#define XROWS  4     // rows p0-1 .. p0+2
#define CC_HALF 4
#define XLDS_BYTES (CC_HALF * XROWS * XPITCH)  // 33,792

__global__ __launch_bounds__(256, 3) void conv_main(const __bf16* __restrict__ xT,
                                                    const __bf16* __restrict__ Wf,
                                                    const float* __restrict__ per,
                                                    float* __restrict__ out) {
    __shared__ __align__(16) char xlds[XLDS_BYTES];

    const int tid  = threadIdx.x;
    const int lane = tid & 63;
    const int w    = tid >> 6;   // 0..3
    const int kbs  = w & 1;      // k half: 0..1
    const int pb   = w >> 1;     // p row within block: 0..1
    const int n    = blockIdx.y;
    const int p0   = blockIdx.x * 2;
    const int m    = lane & 31;
    const int half = lane >> 5;

    // zero pad columns (q=-1 and q=64 slots) for all 16 row-slots, once.
    // Restaging writes only [32,2080) per row, so pads stay zero.
    if (tid < 64) {
        int row = tid >> 2, part = tid & 3;
        int off = row * XPITCH + (part >> 1) * 2080 + (part & 1) * 16;
        *(f32x4*)(xlds + off) = f32x4{0.f, 0.f, 0.f, 0.f};
    }

    f32x16 acc[2][2];  // [kb][qb] = 64 AGPR
#pragma unroll
    for (int b = 0; b < 2; ++b)
#pragma unroll
        for (int c = 0; c < 2; ++c)
#pragma unroll
            for (int e = 0; e < 16; ++e) acc[b][c][e] = 0.f;

    const char* xb = (const char*)xT + ((size_t)n * 8) * PP * QQ * 32;  // + cc*131072

    // stage 4 cc-chunks x 4 rows (p0-1..p0+2): 2048 x 16 B = 8 per thread
    auto stage4 = [&](int ccb) {
#pragma unroll
        for (int it = 0; it < 8; ++it) {
            int id  = it * 256 + tid;       // 0..2047
            int cc4 = id >> 9;              // wave-uniform
            int rem = id & 511;
            int row = rem >> 7;             // wave-uniform (128 chunks/row)
            int wi  = (rem & 127) * 16;
            int r   = p0 - 1 + row;
            int rc  = r < 0 ? 0 : (r > 63 ? 63 : r);
            __builtin_amdgcn_global_load_lds(
                (const __attribute__((address_space(1))) unsigned int*)
                    (xb + (size_t)(ccb + cc4) * 131072 + (size_t)rc * 2048 + wi),
                (__attribute__((address_space(3))) unsigned int*)
                    (xlds + (cc4 * XROWS + row) * XPITCH + 32 + wi),
                16, 0, 0);
        }
    };

    // A fragment base (verified R4/R5): frag id = cc*2304 + (t*4 + kbs*2+kb)*64 + lane
    const bf16x8* wg = (const bf16x8*)Wf + kbs * 128 + lane;

    // one cc-step: B from xlds slot, A from global Wf. Tap-granular load-use.
    auto compute = [&](int slot, int cc) {
        const char* xbase = xlds + slot * (XROWS * XPITCH);
        const bf16x8* wc = wg + (size_t)cc * 2304;

#pragma unroll
        for (int ri = 0; ri < 3; ++ri) {
            const int r = p0 + pb + ri - 1;                 // input row
            const bool rok = ((unsigned)r < (unsigned)PP);  // wave-uniform
            if (rok) {
                const char* rbase = xbase + (pb + ri) * XPITCH + half * 16;
                bf16x8 b[3][2], a[3][2];
#pragma unroll
                for (int dq = 0; dq < 3; ++dq)
#pragma unroll
                    for (int qb = 0; qb < 2; ++qb)
                        b[dq][qb] = *(const bf16x8*)(rbase + (qb * 32 + m + dq) * 32);
#pragma unroll
                for (int dq = 0; dq < 3; ++dq)
#pragma unroll
                    for (int kb = 0; kb < 2; ++kb)
                        a[dq][kb] = wc[((ri * 3 + dq) * 4 + kb) * 64];  // L2 hit
#pragma unroll
                for (int dq = 0; dq < 3; ++dq)
#pragma unroll
                    for (int kb = 0; kb < 2; ++kb)
#pragma unroll
                        for (int qb = 0; qb < 2; ++qb)
                            acc[kb][qb] = __builtin_amdgcn_mfma_f32_32x32x16_bf16(
                                a[dq][kb], b[dq][qb], acc[kb][qb], 0, 0, 0);
            }
        }
    };

    stage4(0);
    __syncthreads();
    compute(0, 0); compute(1, 1); compute(2, 2); compute(3, 3);
    __syncthreads();   // done reading first half
    stage4(4);
    __syncthreads();   // second half ready
    compute(0, 4); compute(1, 5); compute(2, 6);

    // ---- epilogue (verified transpose mapping; tiles = [kb][qb]) ----
    auto tile_addr = [&](int it, int j) -> size_t {
        int kb = it >> 1, qb = it & 1;
        int k = kbs * 64 + kb * 32 + (lane >> 3) + j * 8;
        int q = qb * 32 + (lane & 7) * 4;
        return (((size_t)n * KK + k) * PP + (p0 + pb)) * QQ + q;
    };

    f32x4 pv0[4], pv1[4];
#pragma unroll
    for (int j = 0; j < 4; ++j) pv0[j] = *(const f32x4*)(per + tile_addr(0, j));

    compute(3, 7);

    __syncthreads();   // all waves done with xlds -> safe to reuse as scratch
    float* scr = (float*)(xlds + w * 4096);  // per-wave 4 KB, disjoint

    auto process = [&](int it, f32x4 (&pv)[4]) {
        int kb = it >> 1, qb = it & 1;
        f32x16 v = acc[kb][qb];
#pragma unroll
        for (int r = 0; r < 16; ++r) {
            int kl = (r & 3) + 8 * (r >> 2) + 4 * half;
            scr[kl * 32 + ((((m >> 2) ^ (kl & 7)) << 2) | (m & 3))] = v[r];
        }
        // same-wave LDS RAW: compiler inserts lgkmcnt wait
#pragma unroll
        for (int j = 0; j < 4; ++j) {
            int kl = (lane >> 3) + j * 8;
            f32x4 d = *(const f32x4*)(scr + kl * 32 + (((lane & 7) ^ (kl & 7)) << 2));
            f32x4 s = d + pv[j];
            __builtin_nontemporal_store(s, (f32x4*)(out + tile_addr(it, j)));
        }
    };

#pragma unroll
    for (int itp = 0; itp < 2; ++itp) {
        const int itA = itp * 2, itB = itp * 2 + 1;
#pragma unroll
        for (int j = 0; j < 4; ++j) pv1[j] = *(const f32x4*)(per + tile_addr(itB, j));
        process(itA, pv0);
        if (itp < 1) {
#pragma unroll
            for (int j = 0; j < 4; ++j)
                pv0[j] = *(const f32x4*)(per + tile_addr(itA + 2, j));
        }
        process(itB, pv1);
    }
}

extern "C" void kernel_launch(void* const* d_in, const int* in_sizes, int n_in,
                              void* d_out, int out_size, void* d_ws, size_t ws_size,
                              hipStream_t stream) {
    const float* x   = (const float*)d_in[0];  // [32][128][64][64]
    const float* W   = (const float*)d_in[1];  // [128][1152]
    const float* per = (const float*)d_in[2];  // [32][128][64][64]
    float* out = (float*)d_out;

    __bf16* xT = (__bf16*)d_ws;
    __bf16* Wf = (__bf16*)((char*)d_ws + XT_ELEMS * 2);

    prep_x<<<dim3(PP, NN), 256, 0, stream>>>(x, xT);
    prep_w<<<dim3(72), 256, 0, stream>>>(W, Wf);
    conv_main<<<dim3(PP / 2, NN), 256, 0, stream>>>(xT, Wf, per, out);
}

// Round 7
// 193.146 us; speedup vs baseline: 1.1110x; 1.1098x over previous
//
#include <hip/hip_runtime.h>
#include <hip/hip_bf16.h>

// N,C,K,P,Q,PS = 32,128,128,64,64,3
#define NN 32
#define CCH 128
#define KK 128
#define PP 64
#define QQ 64

typedef __bf16 bf16x8 __attribute__((ext_vector_type(8)));
typedef float f32x16 __attribute__((ext_vector_type(16)));
typedef float f32x4 __attribute__((ext_vector_type(4)));

// Workspace: only Wf now (prep_x is FUSED into conv_main):
//   Wf: [8 cc][9 t][4 kb][64 lane][8 bf16] = 294,912 B

// ---------- prep: W -> Wf fragment order (unchanged — verified) ----------
__global__ __launch_bounds__(256) void prep_w(const float* __restrict__ W,
                                              __bf16* __restrict__ Wf) {
    const int id = blockIdx.x * 256 + threadIdx.x;  // 18432
    const int lane = id & 63;
    const int r1   = id >> 6;
    const int kb   = r1 & 3;
    const int r2   = r1 >> 2;
    const int t    = r2 % 9;
    const int cc   = r2 / 9;

    const int k  = kb * 32 + (lane & 31);
    const int c0 = cc * 16 + (lane >> 5) * 8;

    bf16x8 o;
#pragma unroll
    for (int j = 0; j < 8; ++j)
        o[j] = (__bf16)W[(size_t)k * (CCH * 9) + (size_t)(c0 + j) * 9 + t];
    ((bf16x8*)Wf)[id] = o;
}

// ---------- main: FUSED implicit GEMM conv (prep_x eliminated) ----------
// R0-R6: conv_main 69-82 us invariant under sync/W-path/B-path/epilogue/
// occupancy changes -> stop polishing conv, attack the score's other ~140 us.
// prep_x (~55-65 us + 67 MB HBM round-trip of xT) is deleted: staging now
// reads x (NCHW f32) directly, converts f32->bf16 in-register, and writes
// the SAME LDS layout the verified compute path consumes:
//   task (row 0..5, ch 0..1): lane=q; 8 c-strided dword loads (each
//   wave-instr = contiguous 256 B of x), cvt, pack bf16x8,
//   ds_write_b128 at [row][32 + q*32 + ch*16]  (byte-identical to old xT rows)
// Block: 4 p-rows x 64 q x 128 k, 256 thr; grid (16,32); dbuf, 1 barrier/cc.
// A from global Wf (L2-resident, proven free R4/R5). Epilogue verified (R3).
#define XPITCH 2112  // bytes per padded x row in LDS (66 * 32)
#define XROWS  6
#define XBYTES (XROWS * XPITCH)  // 12,672

__global__ __launch_bounds__(256, 2) void conv_main(const float* __restrict__ x,
                                                    const __bf16* __restrict__ Wf,
                                                    const float* __restrict__ per,
                                                    float* __restrict__ out) {
    __shared__ __align__(16) char xlds[2][XBYTES];   // 25,344
    __shared__ __align__(16) char scr_lds[4][4096];  // per-wave epilogue scratch

    const int tid  = threadIdx.x;
    const int lane = tid & 63;
    const int w    = tid >> 6;   // 0..3
    const int kbs  = w & 1;
    const int pb   = w >> 1;     // 0..1
    const int n    = blockIdx.y;
    const int p0   = blockIdx.x * 4;
    const int m    = lane & 31;
    const int half = lane >> 5;

    // zero the pad columns (q=-1 and q=64 slots) in BOTH buffers, once;
    // staging writes only bytes [32, 2080) per row, so pads stay zero.
    if (tid < 24) {
        int row = tid >> 2, part = tid & 3;
        int off = row * XPITCH + (part >> 1) * 2080 + (part & 1) * 16;
        *(f32x4*)(xlds[0] + off) = f32x4{0.f, 0.f, 0.f, 0.f};
        *(f32x4*)(xlds[1] + off) = f32x4{0.f, 0.f, 0.f, 0.f};
    }

    f32x16 acc[2][2][2];  // [oi][kb][qb]
#pragma unroll
    for (int a = 0; a < 2; ++a)
#pragma unroll
        for (int b = 0; b < 2; ++b)
#pragma unroll
            for (int c = 0; c < 2; ++c)
#pragma unroll
                for (int e = 0; e < 16; ++e) acc[a][b][c][e] = 0.f;

    const float* xn = x + (size_t)n * CCH * PP * QQ;

    // fused stage: x slice (rows p0-1..p0+4, c = ccn*16..+15) -> bf16 LDS.
    // 12 wave-tasks (6 rows x 2 c-halves); 4 waves x 3 iterations.
    auto stage = [&](int ccn, int buf) {
        const float* xs = xn + (size_t)ccn * 16 * PP * QQ;
#pragma unroll
        for (int it = 0; it < 3; ++it) {
            int t4  = it * 4 + w;        // task id, wave-uniform
            int row = t4 >> 1;           // 0..5
            int ch  = t4 & 1;            // c-half
            int r   = p0 - 1 + row;
            int rc  = r < 0 ? 0 : (r > 63 ? 63 : r);
            const float* src = xs + ((size_t)(ch * 8) * PP + rc) * QQ + lane;
            bf16x8 o;
#pragma unroll
            for (int j = 0; j < 8; ++j)
                o[j] = (__bf16)src[(size_t)j * PP * QQ];  // coalesced 256 B/wave-instr
            *(bf16x8*)(xlds[buf] + row * XPITCH + 32 + lane * 32 + ch * 16) = o;
        }
    };

    // A fragment base (verified R4/R5): frag id = cc*2304 + (t*4 + kbs*2+kb)*64 + lane
    const bf16x8* wg = (const bf16x8*)Wf + kbs * 128 + lane;

    // one cc-step; A from Wf (L2-hot), B from xlds[buf] (verified R4 body)
    auto compute = [&](int buf, int cc) {
        const char* xbase = xlds[buf];
        const bf16x8* wc = wg + (size_t)cc * 2304;

        bf16x8 a_cur[3][2], a_prev[3][2];
#pragma unroll
        for (int ri = 0; ri < 4; ++ri) {
            const int rr = pb * 2 + ri;            // xlds row 0..5
            const int r  = p0 + pb * 2 + ri - 1;   // global input row
            const bool rok = ((unsigned)r < (unsigned)PP);  // wave-uniform

            bf16x8 b[3][2];
            if (rok) {
                const char* rbase = xbase + rr * XPITCH + half * 16;
#pragma unroll
                for (int dq = 0; dq < 3; ++dq)
#pragma unroll
                    for (int qb = 0; qb < 2; ++qb)
                        b[dq][qb] = *(const bf16x8*)(rbase + (qb * 32 + m + dq) * 32);
            }

            if (ri < 3) {
#pragma unroll
                for (int dq = 0; dq < 3; ++dq)
#pragma unroll
                    for (int kb = 0; kb < 2; ++kb)
                        a_cur[dq][kb] = wc[((ri * 3 + dq) * 4 + kb) * 64];  // L2 hit
            }

            if (rok) {
                if (ri >= 1) {
#pragma unroll
                    for (int dq = 0; dq < 3; ++dq)
#pragma unroll
                        for (int kb = 0; kb < 2; ++kb)
#pragma unroll
                            for (int qb = 0; qb < 2; ++qb)
                                acc[1][kb][qb] = __builtin_amdgcn_mfma_f32_32x32x16_bf16(
                                    a_prev[dq][kb], b[dq][qb], acc[1][kb][qb], 0, 0, 0);
                }
                if (ri < 3) {
#pragma unroll
                    for (int dq = 0; dq < 3; ++dq)
#pragma unroll
                        for (int kb = 0; kb < 2; ++kb)
#pragma unroll
                            for (int qb = 0; qb < 2; ++qb)
                                acc[0][kb][qb] = __builtin_amdgcn_mfma_f32_32x32x16_bf16(
                                    a_cur[dq][kb], b[dq][qb], acc[0][kb][qb], 0, 0, 0);
                }
            }

            if (ri < 3) {
#pragma unroll
                for (int dq = 0; dq < 3; ++dq)
#pragma unroll
                    for (int kb = 0; kb < 2; ++kb) a_prev[dq][kb] = a_cur[dq][kb];
            }
        }
    };

    stage(0, 0);
    __syncthreads();  // covers pad-zero + stage(0)

    for (int cc = 0; cc < 7; ++cc) {
        stage(cc + 1, (cc + 1) & 1);  // writes the buffer compute isn't reading
        compute(cc & 1, cc);
        __syncthreads();              // stage(cc+1) visible; buf cc&1 free
    }

    // ---- epilogue (verified R3/R4 mapping) ----
    auto tile_addr = [&](int it, int j) -> size_t {
        int oi = it >> 2, kbi = (it >> 1) & 1, qb = it & 1;
        int prow = p0 + pb * 2 + oi;
        int k = (kbs * 2 + kbi) * 32 + (lane >> 3) + j * 8;
        int q = qb * 32 + (lane & 7) * 4;
        return (((size_t)n * KK + k) * PP + prow) * QQ + q;
    };

    float* scr = (float*)scr_lds[w];  // private per wave

    auto process = [&](int it, f32x4 (&pv)[4]) {
        int oi = it >> 2, kbi = (it >> 1) & 1, qb = it & 1;
        f32x16 v = acc[oi][kbi][qb];
#pragma unroll
        for (int r = 0; r < 16; ++r) {
            int kl = (r & 3) + 8 * (r >> 2) + 4 * half;
            scr[kl * 32 + ((((m >> 2) ^ (kl & 7)) << 2) | (m & 3))] = v[r];
        }
        // same-wave LDS RAW: compiler inserts lgkmcnt wait
#pragma unroll
        for (int j = 0; j < 4; ++j) {
            int kl = (lane >> 3) + j * 8;
            f32x4 d = *(const f32x4*)(scr + kl * 32 + (((lane & 7) ^ (kl & 7)) << 2));
            f32x4 s = d + pv[j];
            __builtin_nontemporal_store(s, (f32x4*)(out + tile_addr(it, j)));
        }
    };

    // ---- peeled cc=7 with depth-1 per prefetch (32 VGPR, no spill) ----
    f32x4 pv0[4], pv1[4];
#pragma unroll
    for (int j = 0; j < 4; ++j) pv0[j] = *(const f32x4*)(per + tile_addr(0, j));

    compute(1, 7);  // buf 1, staged during cc=6 iteration

#pragma unroll
    for (int itp = 0; itp < 4; ++itp) {
        const int itA = itp * 2, itB = itp * 2 + 1;
#pragma unroll
        for (int j = 0; j < 4; ++j) pv1[j] = *(const f32x4*)(per + tile_addr(itB, j));
        process(itA, pv0);
        if (itp < 3) {
#pragma unroll
            for (int j = 0; j < 4; ++j)
                pv0[j] = *(const f32x4*)(per + tile_addr(itA + 2, j));
        }
        process(itB, pv1);
    }
}

extern "C" void kernel_launch(void* const* d_in, const int* in_sizes, int n_in,
                              void* d_out, int out_size, void* d_ws, size_t ws_size,
                              hipStream_t stream) {
    const float* x   = (const float*)d_in[0];  // [32][128][64][64]
    const float* W   = (const float*)d_in[1];  // [128][1152]
    const float* per = (const float*)d_in[2];  // [32][128][64][64]
    float* out = (float*)d_out;

    __bf16* Wf = (__bf16*)d_ws;  // 294,912 B

    prep_w<<<dim3(72), 256, 0, stream>>>(W, Wf);
    conv_main<<<dim3(PP / 4, NN), 256, 0, stream>>>(x, Wf, per, out);
}